// Round 2
// baseline (2731.699 us; speedup 1.0000x reference)
//
#include <hip/hip_runtime.h>
#include <cstdint>
#include <cstddef>

#define N_NODES 20000
#define N_EDGES 320000
#define EKCAP   (N_EDGES / 2)   // capacity (rows of 256) for kept-es1 in u1

__device__ __forceinline__ float frelu(float x){ return x > 0.f ? x : 0.f; }
__device__ __forceinline__ float fleaky(float x){ return x > 0.f ? x : 0.2f*x; }

__device__ __forceinline__ float wsum(float v){
  #pragma unroll
  for (int o = 32; o > 0; o >>= 1) v += __shfl_down(v, o);
  return v;
}
__device__ __forceinline__ float wmaxr(float v){
  #pragma unroll
  for (int o = 32; o > 0; o >>= 1) v = fmaxf(v, __shfl_down(v, o));
  return v;
}
__device__ __forceinline__ int wsumi(int v){
  #pragma unroll
  for (int o = 32; o > 0; o >>= 1) v += __shfl_down(v, o);
  return v;
}

// ---------------------------------------------------------------- sgemm
// C[M x Nn] = A1[M x K1] @ B1[K1 x Nn] (+ A2 @ B2) (+ bias). Row-major, ldb = Nn.
__global__ __launch_bounds__(256) void sgemm_k(
    const float* __restrict__ A1, int K1, const float* __restrict__ B1,
    const float* __restrict__ A2, int K2, const float* __restrict__ B2,
    const float* __restrict__ bias, float* __restrict__ C, int M, int Nn)
{
  __shared__ float As[16][68];
  __shared__ float Bs[16][64];
  const int t = threadIdx.x;
  const int m0 = blockIdx.y * 64, n0 = blockIdx.x * 64;
  const int tx = t & 15, ty = t >> 4;
  float acc[4][4] = {{0.f}};
  for (int pass = 0; pass < 2; ++pass) {
    const float* A = pass ? A2 : A1;
    const float* B = pass ? B2 : B1;
    const int K = pass ? K2 : K1;
    if (A == nullptr) continue;
    for (int kt = 0; kt < K; kt += 16) {
      {
        const int row = t >> 2, k4 = (t & 3) * 4;
        const int gm = m0 + row;
        float4 v = make_float4(0.f, 0.f, 0.f, 0.f);
        if (gm < M) v = *(const float4*)(A + (size_t)gm * K + kt + k4);
        As[k4 + 0][row] = v.x; As[k4 + 1][row] = v.y;
        As[k4 + 2][row] = v.z; As[k4 + 3][row] = v.w;
        const int r = t >> 4, c4 = (t & 15) * 4;
        *(float4*)&Bs[r][c4] = *(const float4*)(B + (size_t)(kt + r) * Nn + n0 + c4);
      }
      __syncthreads();
      #pragma unroll
      for (int kk = 0; kk < 16; ++kk) {
        const float4 a = *(const float4*)&As[kk][ty * 4];
        const float4 b = *(const float4*)&Bs[kk][tx * 4];
        acc[0][0] += a.x * b.x; acc[0][1] += a.x * b.y; acc[0][2] += a.x * b.z; acc[0][3] += a.x * b.w;
        acc[1][0] += a.y * b.x; acc[1][1] += a.y * b.y; acc[1][2] += a.y * b.z; acc[1][3] += a.y * b.w;
        acc[2][0] += a.z * b.x; acc[2][1] += a.z * b.y; acc[2][2] += a.z * b.z; acc[2][3] += a.z * b.w;
        acc[3][0] += a.w * b.x; acc[3][1] += a.w * b.y; acc[3][2] += a.w * b.z; acc[3][3] += a.w * b.w;
      }
      __syncthreads();
    }
  }
  float4 bv = make_float4(0.f, 0.f, 0.f, 0.f);
  if (bias) bv = *(const float4*)(bias + n0 + tx * 4);
  #pragma unroll
  for (int i = 0; i < 4; ++i) {
    const int gm = m0 + ty * 4 + i;
    if (gm >= M) continue;
    float4 o;
    o.x = acc[i][0] + bv.x; o.y = acc[i][1] + bv.y;
    o.z = acc[i][2] + bv.z; o.w = acc[i][3] + bv.w;
    *(float4*)(C + (size_t)gm * Nn + n0 + tx * 4) = o;
  }
}

// ---------------------------------------------------------------- edge conv
// m_e = ein_e @ We + P[src] + Q[dst] (bias folded into P). Aggregates into
// xsum[dst] (edges sorted by dst -> run-compressed atomics).
// STOREM: write m (mout0 may alias ein1: each block reads then writes only its
// own rows — safe). WHEAD: fused out_w = sigmoid(relu(m)@Ww + bw) (NOUT=128).
template<int BE, int NOUT, bool RELUIN, bool GATHER, bool STOREM, bool WHEAD>
__global__ __launch_bounds__(256) void econv_k(
    const float* __restrict__ ein0, const float* __restrict__ ein1,
    const float* __restrict__ We,
    const float* __restrict__ P, const float* __restrict__ Q,
    const int* __restrict__ ssrc, const int* __restrict__ sdst,
    const int* __restrict__ seid,
    float* __restrict__ mout0, float* __restrict__ mout1,
    float* __restrict__ xsum,
    const float* __restrict__ wvec, const float* __restrict__ wb,
    float* __restrict__ outw)
{
  constexpr int SA  = 136;          // padded row stride
  constexpr int NC4 = NOUT / 4;     // 32 or 64
  constexpr int TE  = 256 / NC4;
  constexpr int EPT = BE / TE;      // 8 in both configs
  __shared__ float As[BE * SA];
  __shared__ float Ws[32 * NOUT];
  const int t = threadIdx.x;
  const int base = blockIdx.x * BE;
  const int tx = t % NC4, te = t / NC4;
  const int e0 = te * EPT;
  float acc[EPT][4];
  #pragma unroll
  for (int j = 0; j < EPT; ++j) { acc[j][0] = 0.f; acc[j][1] = 0.f; acc[j][2] = 0.f; acc[j][3] = 0.f; }
  const int nbuf = (ein1 != nullptr) ? 2 : 1;
  for (int buf = 0; buf < nbuf; ++buf) {
    const float* ein = buf ? ein1 : ein0;
    __syncthreads();
    for (int i = t; i < BE * 32; i += 256) {
      const int e = i >> 5, k4 = (i & 31) * 4;
      const int g = base + e;
      const size_t row = GATHER ? (size_t)seid[g] : (size_t)g;
      float4 v = *(const float4*)(ein + row * 128 + k4);
      if (RELUIN) { v.x = frelu(v.x); v.y = frelu(v.y); v.z = frelu(v.z); v.w = frelu(v.w); }
      *(float4*)&As[e * SA + k4] = v;
    }
    for (int chunk = 0; chunk < 4; ++chunk) {
      __syncthreads();
      for (int i = t; i < 32 * NC4; i += 256) {
        const int r = i / NC4, c4 = (i % NC4) * 4;
        *(float4*)&Ws[r * NOUT + c4] =
            *(const float4*)(We + (size_t)(buf * 128 + chunk * 32 + r) * NOUT + c4);
      }
      __syncthreads();
      #pragma unroll 4
      for (int kk = 0; kk < 32; ++kk) {
        const float4 w = *(const float4*)&Ws[kk * NOUT + tx * 4];
        #pragma unroll
        for (int j = 0; j < EPT; ++j) {
          const float a = As[(e0 + j) * SA + chunk * 32 + kk];
          acc[j][0] += a * w.x; acc[j][1] += a * w.y;
          acc[j][2] += a * w.z; acc[j][3] += a * w.w;
        }
      }
    }
  }
  float4 wv = make_float4(0.f, 0.f, 0.f, 0.f);
  if constexpr (WHEAD) wv = *(const float4*)(wvec + tx * 4);
  int cur = sdst[base + e0];
  float r0 = 0.f, r1 = 0.f, r2 = 0.f, r3 = 0.f;
  #pragma unroll
  for (int j = 0; j < EPT; ++j) {
    const int g = base + e0 + j;
    const int s = ssrc[g], d = sdst[g];
    const float4 p = *(const float4*)(P + (size_t)s * NOUT + tx * 4);
    const float4 q = *(const float4*)(Q + (size_t)d * NOUT + tx * 4);
    float4 m;
    m.x = acc[j][0] + p.x + q.x; m.y = acc[j][1] + p.y + q.y;
    m.z = acc[j][2] + p.z + q.z; m.w = acc[j][3] + p.w + q.w;
    if constexpr (STOREM) {
      const int c = tx * 4;
      if (NOUT == 128) {
        *(float4*)(mout0 + (size_t)g * 128 + c) = m;
      } else {
        if (c < 128) *(float4*)(mout0 + (size_t)g * 128 + c) = m;
        else         *(float4*)(mout1 + (size_t)g * 128 + (c - 128)) = m;
      }
    }
    if constexpr (WHEAD) {
      float wp = frelu(m.x) * wv.x + frelu(m.y) * wv.y + frelu(m.z) * wv.z + frelu(m.w) * wv.w;
      #pragma unroll
      for (int o = 16; o > 0; o >>= 1) wp += __shfl_down(wp, o);
      if (tx == 0) outw[seid[g]] = 1.f / (1.f + expf(-(wp + wb[0])));
    }
    if (d != cur) {
      float* xs = xsum + (size_t)cur * NOUT + tx * 4;
      atomicAdd(xs + 0, r0); atomicAdd(xs + 1, r1);
      atomicAdd(xs + 2, r2); atomicAdd(xs + 3, r3);
      cur = d; r0 = r1 = r2 = r3 = 0.f;
    }
    r0 += m.x; r1 += m.y; r2 += m.z; r3 += m.w;
  }
  {
    float* xs = xsum + (size_t)cur * NOUT + tx * 4;
    atomicAdd(xs + 0, r0); atomicAdd(xs + 1, r1);
    atomicAdd(xs + 2, r2); atomicAdd(xs + 3, r3);
  }
}

// ---------------------------------------------------------------- presub:
// recompute es1 for kept edges only: es1_i = relu(relu(e3[cidx])@We + P[src]+Q[dst])
__global__ __launch_bounds__(256) void presub_k(
    const float* __restrict__ e3buf, const float* __restrict__ We,
    const float* __restrict__ P, const float* __restrict__ Q,
    const int* __restrict__ csrc, const int* __restrict__ cdst,
    const int* __restrict__ cidx, const int* __restrict__ nKp,
    float* __restrict__ es1out)  // row stride 256
{
  constexpr int BE = 32, SA = 136;
  const int nK = min(*nKp, EKCAP);
  const int base = blockIdx.x * BE;
  if (base >= nK) return;
  __shared__ float As[BE * SA];
  __shared__ float Ws[32 * 256];
  const int t = threadIdx.x;
  const int tx = t & 63, te = t >> 6;
  const int e0 = te * 8;
  float acc[8][4];
  #pragma unroll
  for (int j = 0; j < 8; ++j) { acc[j][0] = 0.f; acc[j][1] = 0.f; acc[j][2] = 0.f; acc[j][3] = 0.f; }
  for (int i = t; i < BE * 32; i += 256) {
    const int e = i >> 5, k4 = (i & 31) * 4;
    const int g = base + e;
    const size_t row = (g < nK) ? (size_t)cidx[g] : 0;
    float4 v = *(const float4*)(e3buf + row * 128 + k4);
    v.x = frelu(v.x); v.y = frelu(v.y); v.z = frelu(v.z); v.w = frelu(v.w);
    *(float4*)&As[e * SA + k4] = v;
  }
  for (int chunk = 0; chunk < 4; ++chunk) {
    __syncthreads();
    for (int i = t; i < 32 * 64; i += 256) {
      const int r = i >> 6, c4 = (i & 63) * 4;
      *(float4*)&Ws[r * 256 + c4] = *(const float4*)(We + (size_t)(chunk * 32 + r) * 256 + c4);
    }
    __syncthreads();
    #pragma unroll 4
    for (int kk = 0; kk < 32; ++kk) {
      const float4 w = *(const float4*)&Ws[kk * 256 + tx * 4];
      #pragma unroll
      for (int j = 0; j < 8; ++j) {
        const float a = As[(e0 + j) * SA + chunk * 32 + kk];
        acc[j][0] += a * w.x; acc[j][1] += a * w.y;
        acc[j][2] += a * w.z; acc[j][3] += a * w.w;
      }
    }
  }
  #pragma unroll
  for (int j = 0; j < 8; ++j) {
    const int g = base + e0 + j;
    if (g < nK) {
      const int s = csrc[g], d = cdst[g];
      const float4 p = *(const float4*)(P + (size_t)s * 256 + tx * 4);
      const float4 q = *(const float4*)(Q + (size_t)d * 256 + tx * 4);
      float4 o;
      o.x = frelu(acc[j][0] + p.x + q.x); o.y = frelu(acc[j][1] + p.y + q.y);
      o.z = frelu(acc[j][2] + p.z + q.z); o.w = frelu(acc[j][3] + p.w + q.w);
      *(float4*)(es1out + (size_t)g * 256 + tx * 4) = o;
    }
  }
}

// ---------------------------------------------------------------- sub conv stage 2
__global__ __launch_bounds__(256) void subconv_k(
    const float* __restrict__ es1, const float* __restrict__ We,
    const float* __restrict__ P, const float* __restrict__ Q,
    const int* __restrict__ csrc, const int* __restrict__ cdst,
    const int* __restrict__ nKp, float* __restrict__ xsum)
{
  constexpr int BE = 64, SA = 136;
  const int nK = min(*nKp, EKCAP);
  const int base = blockIdx.x * BE;
  if (base >= nK) return;
  __shared__ float As[BE * SA];
  __shared__ float Ws[32 * 128];
  const int t = threadIdx.x;
  const int tx = t & 31, te = t >> 5;
  const int e0 = te * 8;
  float acc[8][4];
  #pragma unroll
  for (int j = 0; j < 8; ++j) { acc[j][0] = 0.f; acc[j][1] = 0.f; acc[j][2] = 0.f; acc[j][3] = 0.f; }
  for (int buf = 0; buf < 2; ++buf) {
    __syncthreads();
    for (int i = t; i < BE * 32; i += 256) {
      const int e = i >> 5, k4 = (i & 31) * 4;
      const size_t row = (size_t)(base + e);
      *(float4*)&As[e * SA + k4] = *(const float4*)(es1 + row * 256 + buf * 128 + k4);
    }
    for (int chunk = 0; chunk < 4; ++chunk) {
      __syncthreads();
      for (int i = t; i < 32 * 32; i += 256) {
        const int r = i >> 5, c4 = (i & 31) * 4;
        *(float4*)&Ws[r * 128 + c4] =
            *(const float4*)(We + (size_t)(buf * 128 + chunk * 32 + r) * 128 + c4);
      }
      __syncthreads();
      #pragma unroll 4
      for (int kk = 0; kk < 32; ++kk) {
        const float4 w = *(const float4*)&Ws[kk * 128 + tx * 4];
        #pragma unroll
        for (int j = 0; j < 8; ++j) {
          const float a = As[(e0 + j) * SA + chunk * 32 + kk];
          acc[j][0] += a * w.x; acc[j][1] += a * w.y;
          acc[j][2] += a * w.z; acc[j][3] += a * w.w;
        }
      }
    }
  }
  int cur = -1;
  float r0 = 0.f, r1 = 0.f, r2 = 0.f, r3 = 0.f;
  #pragma unroll
  for (int j = 0; j < 8; ++j) {
    const int g = base + e0 + j;
    if (g < nK) {
      const int s = csrc[g], d = cdst[g];
      const float4 p = *(const float4*)(P + (size_t)s * 128 + tx * 4);
      const float4 q = *(const float4*)(Q + (size_t)d * 128 + tx * 4);
      const float mx = acc[j][0] + p.x + q.x, my = acc[j][1] + p.y + q.y;
      const float mz = acc[j][2] + p.z + q.z, mw = acc[j][3] + p.w + q.w;
      if (d != cur) {
        if (cur >= 0) {
          float* xs = xsum + (size_t)cur * 128 + tx * 4;
          atomicAdd(xs + 0, r0); atomicAdd(xs + 1, r1);
          atomicAdd(xs + 2, r2); atomicAdd(xs + 3, r3);
        }
        cur = d; r0 = r1 = r2 = r3 = 0.f;
      }
      r0 += mx; r1 += my; r2 += mz; r3 += mw;
    }
  }
  if (cur >= 0) {
    float* xs = xsum + (size_t)cur * 128 + tx * 4;
    atomicAdd(xs + 0, r0); atomicAdd(xs + 1, r1);
    atomicAdd(xs + 2, r2); atomicAdd(xs + 3, r3);
  }
}

// ---------------------------------------------------------------- small kernels
__global__ void hist_k(const int* __restrict__ dst, int* __restrict__ deg, int E){
  const int e = blockIdx.x * 256 + threadIdx.x;
  if (e < E) atomicAdd(&deg[dst[e]], 1);
}

__global__ __launch_bounds__(1024) void scan_deg_k(
    const int* __restrict__ deg, int* __restrict__ rowstart, int* __restrict__ cursor,
    float* __restrict__ recip, int n)
{
  __shared__ int sb[1024];
  __shared__ int carry;
  const int t = threadIdx.x;
  if (t == 0) carry = 0;
  __syncthreads();
  const int CH = (n + 1023) >> 10;
  for (int c = 0; c < CH; ++c) {
    const int i = c * 1024 + t;
    const int d = (i < n) ? deg[i] : 0;
    sb[t] = d;
    __syncthreads();
    for (int off = 1; off < 1024; off <<= 1) {
      const int v = (t >= off) ? sb[t - off] : 0;
      __syncthreads();
      sb[t] += v;
      __syncthreads();
    }
    const int excl = sb[t] - d;
    const int tot = sb[1023];
    if (i < n) {
      const int rs = carry + excl;
      rowstart[i] = rs; cursor[i] = rs;
      recip[i] = 1.0f / (float)max(d, 1);
    }
    __syncthreads();
    if (t == 0) carry += tot;
    __syncthreads();
  }
  if (t == 0) rowstart[n] = carry;
}

__global__ void scatter_k(const int* __restrict__ src, const int* __restrict__ dst,
                          int* __restrict__ cursor, int* __restrict__ ssrc,
                          int* __restrict__ sdst, int* __restrict__ seid, int E){
  const int e = blockIdx.x * 256 + threadIdx.x;
  if (e < E) {
    const int d = dst[e];
    const int pos = atomicAdd(&cursor[d], 1);
    ssrc[pos] = src[e]; sdst[pos] = d; seid[pos] = e;
  }
}

__global__ void meanrelu_k(const float* __restrict__ xsum, const float* __restrict__ recip,
                           float* __restrict__ out, int total, int shift){
  const int i = blockIdx.x * 256 + threadIdx.x;
  if (i < total) out[i] = frelu(xsum[i] * recip[i >> shift]);
}

__global__ void h_k(const float* __restrict__ xs1, const float* __restrict__ Wg,
                    float* __restrict__ h, int n){
  const int node = blockIdx.x * 4 + (threadIdx.x >> 6);
  const int lane = threadIdx.x & 63;
  if (node >= n) return;
  const float4 x = *(const float4*)(xs1 + (size_t)node * 256 + lane * 4);
  const float4 w = *(const float4*)(Wg + lane * 4);
  float v = x.x * w.x + x.y * w.y + x.z * w.z + x.w * w.w;
  v = wsum(v);
  if (lane == 0) h[node] = v;
}

__global__ void att_k(const float* __restrict__ h, const int* __restrict__ rowstart,
                      const int* __restrict__ ssrc, const float* __restrict__ asp,
                      const float* __restrict__ adp, float* __restrict__ score, int n){
  const int node = blockIdx.x * 4 + (threadIdx.x >> 6);
  const int lane = threadIdx.x & 63;
  if (node >= n) return;
  const float a_s = asp[0], a_d = adp[0];
  const float hv = h[node];
  const int s0 = rowstart[node], s1 = rowstart[node + 1];
  const float selfea = fleaky(hv * (a_s + a_d));
  float mx = selfea;
  for (int i = s0 + lane; i < s1; i += 64) {
    const float hs = h[ssrc[i]];
    mx = fmaxf(mx, fleaky(hs * a_s + hv * a_d));
  }
  mx = wmaxr(mx);
  mx = __shfl(mx, 0);
  float den = 0.f, num = 0.f;
  if (lane == 0) { const float ez = expf(selfea - mx); den = ez; num = ez * hv; }
  for (int i = s0 + lane; i < s1; i += 64) {
    const float hs = h[ssrc[i]];
    const float ez = expf(fleaky(hs * a_s + hv * a_d) - mx);
    den += ez; num += ez * hs;
  }
  den = wsum(den); num = wsum(num);
  if (lane == 0) score[node] = num / den;
}

__device__ __forceinline__ unsigned keymap(float s){
  unsigned u = __float_as_uint(s);
  return (u & 0x80000000u) ? ~u : (u | 0x80000000u);
}

__global__ __launch_bounds__(1024) void topk_k(const float* __restrict__ score,
                                               int* __restrict__ kept,
                                               float* __restrict__ tfac, int n, int k)
{
  const int t = threadIdx.x;
  constexpr int CH = 20;  // covers n <= 20480
  unsigned key[CH];
  float sc[CH];
  #pragma unroll
  for (int c = 0; c < CH; ++c) {
    const int i = c * 1024 + t;
    if (i < n) { const float s = score[i]; sc[c] = s; key[c] = keymap(s); }
    else       { sc[c] = 0.f; key[c] = 0u; }
  }
  __shared__ int cnt;
  __shared__ int sb[1024];
  __shared__ int carry_eq;
  unsigned vstar = 0u;
  for (int b = 31; b >= 0; --b) {
    const unsigned cand = vstar | (1u << b);
    if (t == 0) cnt = 0;
    __syncthreads();
    int local = 0;
    #pragma unroll
    for (int c = 0; c < CH; ++c) local += (key[c] >= cand) ? 1 : 0;
    local = wsumi(local);
    if ((t & 63) == 0) atomicAdd(&cnt, local);
    __syncthreads();
    if (cnt >= k) vstar = cand;
    __syncthreads();
  }
  if (t == 0) cnt = 0;
  __syncthreads();
  {
    int local = 0;
    #pragma unroll
    for (int c = 0; c < CH; ++c) local += (key[c] > vstar) ? 1 : 0;
    local = wsumi(local);
    if ((t & 63) == 0) atomicAdd(&cnt, local);
  }
  __syncthreads();
  const int need = k - cnt;  // ties kept by lowest index
  if (t == 0) carry_eq = 0;
  __syncthreads();
  for (int c = 0; c < CH; ++c) {
    const int i = c * 1024 + t;
    const int flag = (i < n && key[c] == vstar) ? 1 : 0;
    sb[t] = flag;
    __syncthreads();
    for (int off = 1; off < 1024; off <<= 1) {
      const int v = (t >= off) ? sb[t - off] : 0;
      __syncthreads();
      sb[t] += v;
      __syncthreads();
    }
    const int rank = sb[t] - flag;
    const int tot = sb[1023];
    if (i < n) {
      const bool kp = (key[c] > vstar) || (flag && (carry_eq + rank) < need);
      kept[i] = kp ? 1 : 0;
      tfac[i] = kp ? tanhf(sc[c]) : 0.f;
    }
    __syncthreads();
    if (t == 0) carry_eq += tot;
    __syncthreads();
  }
}

__global__ void xpip_k(float* __restrict__ xs1, const float* __restrict__ tf, int total){
  const int i = blockIdx.x * 256 + threadIdx.x;
  if (i < total) xs1[i] *= tf[i >> 8];
}

__global__ __launch_bounds__(256) void flagsum_k(const int* __restrict__ kept,
    const int* __restrict__ ssrc, const int* __restrict__ sdst,
    int* __restrict__ bsum, int E){
  const int t = threadIdx.x;
  const int base = blockIdx.x * 1024;
  int loc = 0;
  #pragma unroll
  for (int j = 0; j < 4; ++j) {
    const int e = base + t * 4 + j;
    if (e < E) loc += kept[ssrc[e]] & kept[sdst[e]];
  }
  loc = wsumi(loc);
  __shared__ int wsh[4];
  if ((t & 63) == 0) wsh[t >> 6] = loc;
  __syncthreads();
  if (t == 0) bsum[blockIdx.x] = wsh[0] + wsh[1] + wsh[2] + wsh[3];
}

__global__ __launch_bounds__(512) void scanb_k(int* __restrict__ bsum, int nb, int* __restrict__ Ek){
  __shared__ int sb[512];
  const int t = threadIdx.x;
  const int v = (t < nb) ? bsum[t] : 0;
  sb[t] = v;
  __syncthreads();
  for (int off = 1; off < 512; off <<= 1) {
    const int u = (t >= off) ? sb[t - off] : 0;
    __syncthreads();
    sb[t] += u;
    __syncthreads();
  }
  if (t < nb) bsum[t] = sb[t] - v;   // exclusive
  if (t == 511) *Ek = sb[511];
}

__global__ __launch_bounds__(256) void compact_k(const int* __restrict__ kept,
    const int* __restrict__ ssrc, const int* __restrict__ sdst,
    const int* __restrict__ bsum, int* __restrict__ csrc, int* __restrict__ cdst,
    int* __restrict__ cidx, int* __restrict__ cntk, int E){
  const int t = threadIdx.x;
  const int base = blockIdx.x * 1024;
  int f[4]; int s = 0;
  #pragma unroll
  for (int j = 0; j < 4; ++j) {
    const int e = base + t * 4 + j;
    f[j] = (e < E) ? (kept[ssrc[e]] & kept[sdst[e]]) : 0;
    s += f[j];
  }
  __shared__ int sb[256];
  sb[t] = s;
  __syncthreads();
  for (int off = 1; off < 256; off <<= 1) {
    const int u = (t >= off) ? sb[t - off] : 0;
    __syncthreads();
    sb[t] += u;
    __syncthreads();
  }
  int pos = bsum[blockIdx.x] + sb[t] - s;
  #pragma unroll
  for (int j = 0; j < 4; ++j) {
    if (f[j]) {
      const int e = base + t * 4 + j;
      csrc[pos] = ssrc[e]; cdst[pos] = sdst[e]; cidx[pos] = e;
      atomicAdd(&cntk[sdst[e]], 1);
      ++pos;
    }
  }
}

__global__ void submerge_k(const float* __restrict__ x3, const float* __restrict__ xsum,
                           const int* __restrict__ cntk, const int* __restrict__ kept,
                           float* __restrict__ x32, int total){
  const int i = blockIdx.x * 256 + threadIdx.x;
  if (i >= total) return;
  const int v = i >> 7;
  float add = 0.f;
  if (kept[v]) {
    float c = (float)cntk[v];
    c = c > 0.f ? c : 1.f;
    add = frelu(xsum[i] / c);
  }
  x32[i] = x3[i] + add;
}

__global__ void fnode_k(const float* __restrict__ xsum, const float* __restrict__ recip,
                        const float* __restrict__ Wl1, const float* __restrict__ bl1,
                        float* __restrict__ out, int n){
  const int node = blockIdx.x * 4 + (threadIdx.x >> 6);
  const int lane = threadIdx.x & 63;
  if (node >= n) return;
  const float rc = recip[node];
  const float2 xv = *(const float2*)(xsum + (size_t)node * 128 + lane * 2);
  const float2 wv = *(const float2*)(Wl1 + lane * 2);
  float v = frelu(xv.x * rc) * wv.x + frelu(xv.y * rc) * wv.y;
  v = wsum(v);
  if (lane == 0) out[node] = 1.f / (1.f + expf(-(v + bl1[0])));
}

// ---------------------------------------------------------------- launch
extern "C" void kernel_launch(void* const* d_in, const int* in_sizes, int n_in,
                              void* d_out, int out_size, void* d_ws, size_t ws_size,
                              hipStream_t stream)
{
  const int N = N_NODES, E = N_EDGES;
  const float* node_feat = (const float*)d_in[0];
  const float* edge_feat = (const float*)d_in[1];
  const int*   eidx      = (const int*)d_in[2];
  const float* W_red = (const float*)d_in[3];  const float* b_red = (const float*)d_in[4];
  const float* W1 = (const float*)d_in[5];   const float* b1 = (const float*)d_in[6];
  const float* W2 = (const float*)d_in[7];   const float* b2 = (const float*)d_in[8];
  const float* W3 = (const float*)d_in[9];   const float* b3 = (const float*)d_in[10];
  const float* Wpre = (const float*)d_in[11]; const float* bpre = (const float*)d_in[12];
  const float* Wsub = (const float*)d_in[13]; const float* bsub = (const float*)d_in[14];
  const float* W4 = (const float*)d_in[15];  const float* b4 = (const float*)d_in[16];
  const float* Wg = (const float*)d_in[17];
  const float* a_s = (const float*)d_in[18]; const float* a_d = (const float*)d_in[19];
  const float* Wl1 = (const float*)d_in[20]; const float* bl1 = (const float*)d_in[21];
  const float* Ww = (const float*)d_in[22];  const float* bw = (const float*)d_in[23];
  float* out_x = (float*)d_out;
  float* out_w = out_x + N;

  char* wsb = (char*)d_ws;
  size_t off = 0;
  auto alloc = [&](size_t bytes) -> void* {
    void* p = wsb + off;
    off = (off + bytes + 255) & ~(size_t)255;
    return p;
  };
  // total ~449 MB
  float* u1   = (float*)alloc((size_t)E * 128 * 4);   // e1 -> e3a -> kept-es1(256-stride)
  float* u2   = (float*)alloc((size_t)E * 128 * 4);   // e2 -> e3
  float* n1   = (float*)alloc((size_t)N * 128 * 4);   // x0 -> x3a -> Psub -> x32
  float* n2   = (float*)alloc((size_t)N * 128 * 4);   // x1 -> x3
  float* n3   = (float*)alloc((size_t)N * 128 * 4);   // x2 -> Qsub
  float* xs1  = (float*)alloc((size_t)N * 256 * 4);   // xs1 -> xp (in place)
  float* P    = (float*)alloc((size_t)N * 256 * 4);
  float* Qb   = (float*)alloc((size_t)N * 256 * 4);
  float* xsum = (float*)alloc((size_t)N * 256 * 4);
  int* ssrc = (int*)alloc((size_t)E * 4);
  int* sdst = (int*)alloc((size_t)E * 4);
  int* seid = (int*)alloc((size_t)E * 4);
  int* csrc = (int*)alloc((size_t)E * 4);
  int* cdst = (int*)alloc((size_t)E * 4);
  int* cidx = (int*)alloc((size_t)E * 4);
  int* deg     = (int*)alloc((size_t)N * 4);
  int* cursor  = (int*)alloc((size_t)N * 4);
  int* rowstart= (int*)alloc((size_t)(N + 1) * 4);
  int* kept    = (int*)alloc((size_t)N * 4);
  int* cntk    = (int*)alloc((size_t)N * 4);
  float* recip = (float*)alloc((size_t)N * 4);
  float* hbuf  = (float*)alloc((size_t)N * 4);
  float* score = (float*)alloc((size_t)N * 4);
  float* tfac  = (float*)alloc((size_t)N * 4);
  int* bsum    = (int*)alloc(1024 * 4);
  int* Ek      = (int*)alloc(256);
  (void)ws_size; (void)in_sizes; (void)n_in; (void)out_size;

  const dim3 g128(2, (N + 63) / 64), g256(4, (N + 63) / 64);
  const int nbFS = (E + 1023) / 1024;
  #define NILS nullptr, nullptr, nullptr

  // ---- sort edges by dst (counting sort) ----
  hipMemsetAsync(deg, 0, (size_t)N * 4, stream);
  hist_k<<<(E + 255) / 256, 256, 0, stream>>>(eidx + E, deg, E);
  scan_deg_k<<<1, 1024, 0, stream>>>(deg, rowstart, cursor, recip, N);
  scatter_k<<<(E + 255) / 256, 256, 0, stream>>>(eidx, eidx + E, cursor, ssrc, sdst, seid, E);

  // ---- x0 = node_feat @ W_red + b_red -> n1 ----
  sgemm_k<<<g128, 256, 0, stream>>>(node_feat, 256, W_red, nullptr, 0, nullptr, b_red, n1, N, 128);

  // ---- conv1: e in edge_feat, out u1; x1 -> n2 ----
  sgemm_k<<<g128, 256, 0, stream>>>(n1, 128, W1,             nullptr, 0, nullptr, b1,      P,  N, 128);
  sgemm_k<<<g128, 256, 0, stream>>>(n1, 128, W1 + 128 * 128, nullptr, 0, nullptr, nullptr, Qb, N, 128);
  hipMemsetAsync(xsum, 0, (size_t)N * 128 * 4, stream);
  econv_k<64, 128, false, true, true, false><<<E / 64, 256, 0, stream>>>(
      edge_feat, nullptr, W1 + 256 * 128, P, Qb, ssrc, sdst, seid, u1, nullptr, xsum, NILS);
  meanrelu_k<<<(N * 128) / 256, 256, 0, stream>>>(xsum, recip, n2, N * 128, 7);

  // ---- conv2: in u1(e1), out u2; x2 -> n3 ----
  sgemm_k<<<g128, 256, 0, stream>>>(n2, 128, W2,             nullptr, 0, nullptr, b2,      P,  N, 128);
  sgemm_k<<<g128, 256, 0, stream>>>(n2, 128, W2 + 128 * 128, nullptr, 0, nullptr, nullptr, Qb, N, 128);
  hipMemsetAsync(xsum, 0, (size_t)N * 128 * 4, stream);
  econv_k<64, 128, true, false, true, false><<<E / 64, 256, 0, stream>>>(
      u1, nullptr, W2 + 256 * 128, P, Qb, ssrc, sdst, seid, u2, nullptr, xsum, NILS);
  meanrelu_k<<<(N * 128) / 256, 256, 0, stream>>>(xsum, recip, n3, N * 128, 7);

  // ---- conv3 (first): xin=[x2,x1], ein=[e2,e1]; e3a overwrites u1 in place; x3a -> n1 ----
  sgemm_k<<<g128, 256, 0, stream>>>(n3, 128, W3,             n2, 128, W3 + 128 * 128, b3,      P,  N, 128);
  sgemm_k<<<g128, 256, 0, stream>>>(n3, 128, W3 + 256 * 128, n2, 128, W3 + 384 * 128, nullptr, Qb, N, 128);
  hipMemsetAsync(xsum, 0, (size_t)N * 128 * 4, stream);
  econv_k<64, 128, true, false, true, false><<<E / 64, 256, 0, stream>>>(
      u2, u1, W3 + 512 * 128, P, Qb, ssrc, sdst, seid, u1, nullptr, xsum, NILS);
  meanrelu_k<<<(N * 128) / 256, 256, 0, stream>>>(xsum, recip, n1, N * 128, 7);

  // ---- conv3 (second, shared W3): xin=[x3a,x2], ein=[e3a,e2]; e3 overwrites u2; x3 -> n2 ----
  sgemm_k<<<g128, 256, 0, stream>>>(n1, 128, W3,             n3, 128, W3 + 128 * 128, b3,      P,  N, 128);
  sgemm_k<<<g128, 256, 0, stream>>>(n1, 128, W3 + 256 * 128, n3, 128, W3 + 384 * 128, nullptr, Qb, N, 128);
  hipMemsetAsync(xsum, 0, (size_t)N * 128 * 4, stream);
  econv_k<64, 128, true, false, true, false><<<E / 64, 256, 0, stream>>>(
      u1, u2, W3 + 512 * 128, P, Qb, ssrc, sdst, seid, u2, nullptr, xsum, NILS);
  meanrelu_k<<<(N * 128) / 256, 256, 0, stream>>>(xsum, recip, n2, N * 128, 7);

  // ---- pre conv (NOUT=256), aggregate only (es1 NOT stored); xs1 ----
  sgemm_k<<<g256, 256, 0, stream>>>(n2, 128, Wpre,             nullptr, 0, nullptr, bpre,    P,  N, 256);
  sgemm_k<<<g256, 256, 0, stream>>>(n2, 128, Wpre + 128 * 256, nullptr, 0, nullptr, nullptr, Qb, N, 256);
  hipMemsetAsync(xsum, 0, (size_t)N * 256 * 4, stream);
  econv_k<32, 256, true, false, false, false><<<E / 32, 256, 0, stream>>>(
      u2, nullptr, Wpre + 256 * 256, P, Qb, ssrc, sdst, seid, nullptr, nullptr, xsum, NILS);
  meanrelu_k<<<(N * 256) / 256, 256, 0, stream>>>(xsum, recip, xs1, N * 256, 8);

  // ---- SAGPool scorer + top-k; xp in-place over xs1 ----
  h_k<<<(N + 3) / 4, 256, 0, stream>>>(xs1, Wg, hbuf, N);
  att_k<<<(N + 3) / 4, 256, 0, stream>>>(hbuf, rowstart, ssrc, a_s, a_d, score, N);
  topk_k<<<1, 1024, 0, stream>>>(score, kept, tfac, N, N / 2);
  xpip_k<<<(N * 256) / 256, 256, 0, stream>>>(xs1, tfac, N * 256);

  // ---- compact kept edges ----
  hipMemsetAsync(cntk, 0, (size_t)N * 4, stream);
  flagsum_k<<<nbFS, 256, 0, stream>>>(kept, ssrc, sdst, bsum, E);
  scanb_k<<<1, 512, 0, stream>>>(bsum, nbFS, Ek);
  compact_k<<<nbFS, 256, 0, stream>>>(kept, ssrc, sdst, bsum, csrc, cdst, cidx, cntk, E);

  // ---- sub conv: Psub -> n1 (x3a dead), Qsub -> n3 (x2 dead) ----
  sgemm_k<<<g128, 256, 0, stream>>>(xs1, 256, Wsub,             nullptr, 0, nullptr, bsub,    n1, N, 128);
  sgemm_k<<<g128, 256, 0, stream>>>(xs1, 256, Wsub + 256 * 128, nullptr, 0, nullptr, nullptr, n3, N, 128);
  // recompute es1 for kept edges into u1 (e3a dead); P/Qb still hold Ppre/Qpre
  presub_k<<<(EKCAP + 31) / 32, 256, 0, stream>>>(
      u2, Wpre + 256 * 256, P, Qb, csrc, cdst, cidx, Ek, u1);
  hipMemsetAsync(xsum, 0, (size_t)N * 128 * 4, stream);
  subconv_k<<<(EKCAP + 63) / 64, 256, 0, stream>>>(
      u1, Wsub + 512 * 128, n1, n3, csrc, cdst, Ek, xsum);
  submerge_k<<<(N * 128) / 256, 256, 0, stream>>>(n2, xsum, cntk, kept, n1, N * 128);

  // ---- conv4: xin=[x3_2(n1), x3(n2)], ein=e3(u2); fused w-head, no m store ----
  sgemm_k<<<g128, 256, 0, stream>>>(n1, 128, W4,             n2, 128, W4 + 128 * 128, b4,      P,  N, 128);
  sgemm_k<<<g128, 256, 0, stream>>>(n1, 128, W4 + 256 * 128, n2, 128, W4 + 384 * 128, nullptr, Qb, N, 128);
  hipMemsetAsync(xsum, 0, (size_t)N * 128 * 4, stream);
  econv_k<64, 128, true, false, false, true><<<E / 64, 256, 0, stream>>>(
      u2, nullptr, W4 + 512 * 128, P, Qb, ssrc, sdst, seid, nullptr, nullptr, xsum, Ww, bw, out_w);

  // ---- node head ----
  fnode_k<<<(N + 3) / 4, 256, 0, stream>>>(xsum, recip, Wl1, bl1, out_x, N);
  #undef NILS
}